// Round 3
// baseline (831.135 us; speedup 1.0000x reference)
//
#include <hip/hip_runtime.h>
#include <hip/hip_bf16.h>
#include <math.h>

#define NN 8192
#define FF 64
#define HH 128
#define RR 3
#define DEG 32
#define KK 32
#define EE (NN*DEG)
#define DD 131            // 2F+3
#define TEMP 0.3f
#define NEG_SLOPE 0.2f
#define EPS_LN 1e-5f
#define W_THRESH 1e-6f

__device__ __forceinline__ float4 ld4(const float* p) { return *(const float4*)p; }

// ws layout (floats): [0]=contagion_sum [1..3]=regime_probs [4]=amp [8..71]=colsum
// [128 .. 128+E) = edge scores

// ---------------- Kernel A: column sums of x + contagion level ----------------
__global__ __launch_bounds__(256) void stats_kernel(
    const float* __restrict__ x, const float* __restrict__ Wc1,
    const float* __restrict__ bc1, const float* __restrict__ Wc2,
    const float* __restrict__ bc2, float* __restrict__ hdr)
{
    __shared__ float xs[64 * 65];
    __shared__ float wl[64 * 128];
    __shared__ float cs[4][64];
    int t = threadIdx.x;
    int n0 = blockIdx.x * 64;

    for (int i = 0; i < 16; i++) {
        int flat = t + i * 256;
        int r = flat >> 6, c = flat & 63;
        xs[r * 65 + c] = x[(n0 + r) * 64 + c];
    }
    for (int i = 0; i < 32; i++) {
        int flat = t + i * 256;
        wl[flat] = Wc1[flat];
    }
    __syncthreads();

    {
        int col = t & 63, g = t >> 6;
        float ps = 0.f;
        for (int r = g * 16; r < g * 16 + 16; r++) ps += xs[r * 65 + col];
        cs[g][col] = ps;
    }
    __syncthreads();
    if (t < 64) {
        float v = cs[0][t] + cs[1][t] + cs[2][t] + cs[3][t];
        atomicAdd(&hdr[8 + t], v);
    }

    int r = t >> 2, q = t & 3;
    float accl = 0.f;
    for (int hh = 0; hh < 32; hh++) {
        int h = hh * 4 + q;
        float s = bc1[h];
        for (int i = 0; i < 64; i++) s += xs[r * 65 + i] * wl[i * 128 + h];
        accl += fmaxf(s, 0.f) * Wc2[h];
    }
    accl += __shfl_xor(accl, 1);
    accl += __shfl_xor(accl, 2);
    if (q == 0) {
        float lvl = 1.f / (1.f + expf(-(accl + bc2[0])));
        atomicAdd(&hdr[0], lvl);
    }
}

// ---------------- Kernel B: regime probs + amp ----------------
__global__ __launch_bounds__(128) void regime_kernel(
    const float* __restrict__ Wr1, const float* __restrict__ br1,
    const float* __restrict__ Wr2, const float* __restrict__ br2,
    float* __restrict__ hdr)
{
    __shared__ float gsl[64];
    __shared__ float t1[128];
    int t = threadIdx.x;
    if (t < 64) gsl[t] = hdr[8 + t] * (1.f / (float)NN);
    __syncthreads();
    float a = br1[t];
    for (int i = 0; i < 64; i++) a += gsl[i] * Wr1[i * 128 + t];
    t1[t] = fmaxf(a, 0.f);
    __syncthreads();
    if (t < 3) {
        float v = br2[t];
        for (int h = 0; h < 128; h++) v += t1[h] * Wr2[h * 3 + t];
        gsl[32 + t] = v;
    }
    __syncthreads();
    if (t == 0) {
        float v0 = gsl[32], v1 = gsl[33], v2 = gsl[34];
        float m = fmaxf(v0, fmaxf(v1, v2));
        float e0 = expf(v0 - m), e1 = expf(v1 - m), e2 = expf(v2 - m);
        float inv = 1.f / (e0 + e1 + e2);
        hdr[1] = e0 * inv; hdr[2] = e1 * inv; hdr[3] = e2 * inv;
        hdr[4] = 1.f + 0.5f * (hdr[0] * (1.f / (float)NN));
    }
}

// ---------------- Edge-score kernel: round-1-identical numerics, restructured ----------------
// block = 256 threads, tile = 64 edges (2 src nodes), grid = E/64.
// LDS pool (floats):
//   phase A: EI[64*140]            at 0      (8960)
//   phase B: ehT[128*68]           at 0      (8704)   (aliases EI, after sync)
//            Gbuf[64*65]           at 8704   (4160)
//   always : rawS at 12864, gateC at 12928; pool = 12992 floats = 51968 B
#define EHT_STRIDE 68
__global__ __launch_bounds__(256) void edge_score_kernel(
    const float* __restrict__ x, const int* __restrict__ tgt_idx,
    const float* __restrict__ edge_attr,
    const float* __restrict__ Ws1, const float* __restrict__ bs1,
    const float* __restrict__ ln_g, const float* __restrict__ ln_b,
    const float* __restrict__ Ws2, const float* __restrict__ bs2,
    const float* __restrict__ Wp, const float* __restrict__ bp,
    const float* __restrict__ Wg1, const float* __restrict__ bg1,
    const float* __restrict__ Wg2, const float* __restrict__ bg2,
    const float* __restrict__ hdr, float* __restrict__ scores)
{
    __shared__ float pool[12992];
    float* EI    = pool;            // [64][140]
    float* ehT   = pool;            // [128][EHT_STRIDE]
    float* Gbuf  = pool + 8704;     // [64][65]
    float* rawS  = pool + 12864;    // [64]
    float* gateC = pool + 12928;    // [64]

    int t = threadIdx.x;
    int e0 = blockIdx.x * 64;

    // ---- stage edge_input (identical to round 1: stride 140, zero-pad tail) ----
    {
        int r = t >> 2, q = t & 3;
        int e = e0 + r;
        int src = e >> 5;
        int tg = tgt_idx[e];
        for (int ii = q; ii < 140; ii += 4) {
            float v;
            if (ii < 64) v = x[src * 64 + ii];
            else if (ii < 128) v = x[tg * 64 + (ii - 64)];
            else if (ii < 131) v = edge_attr[e * 3 + (ii - 128)];
            else v = 0.f;
            EI[r * 140 + ii] = v;
        }
    }
    __syncthreads();

    int tcol = t & 7, trow = t >> 3;       // cols: tcol*4 + j*32 + c ; rows: 2*trow, 2*trow+1
    const float* EIr0 = &EI[(2 * trow) * 140];
    const float* EIr1 = EIr0 + 140;

    float acc0[16], acc1[16];

    // ================= GEMM 1: h = EI @ Ws1 (k-sequential, weights from global) =================
    #pragma unroll
    for (int j = 0; j < 16; j++) { acc0[j] = 0.f; acc1[j] = 0.f; }
    for (int k = 0; k < 131; k++) {
        float a0 = EIr0[k];
        float a1 = EIr1[k];
        const float* wrow = &Ws1[k * 128 + tcol * 4];
        #pragma unroll
        for (int j = 0; j < 4; j++) {
            float4 w = ld4(wrow + j * 32);
            acc0[j*4+0] += a0 * w.x; acc0[j*4+1] += a0 * w.y;
            acc0[j*4+2] += a0 * w.z; acc0[j*4+3] += a0 * w.w;
            acc1[j*4+0] += a1 * w.x; acc1[j*4+1] += a1 * w.y;
            acc1[j*4+2] += a1 * w.z; acc1[j*4+3] += a1 * w.w;
        }
    }

    // ---- +bias, LayerNorm, LeakyReLU, dot Ws2 (verbatim round-1) ----
    {
        float s0 = 0.f, ss0 = 0.f, s1 = 0.f, ss1 = 0.f;
        #pragma unroll
        for (int j = 0; j < 16; j++) {
            int col = tcol * 4 + (j >> 2) * 32 + (j & 3);
            float b = bs1[col];
            acc0[j] += b; acc1[j] += b;
            s0 += acc0[j]; ss0 += acc0[j] * acc0[j];
            s1 += acc1[j]; ss1 += acc1[j] * acc1[j];
        }
        #pragma unroll
        for (int m = 1; m < 8; m <<= 1) {
            s0 += __shfl_xor(s0, m);  ss0 += __shfl_xor(ss0, m);
            s1 += __shfl_xor(s1, m);  ss1 += __shfl_xor(ss1, m);
        }
        float mu0 = s0 * (1.f / 128.f), mu1 = s1 * (1.f / 128.f);
        float var0 = ss0 * (1.f / 128.f) - mu0 * mu0;
        float var1 = ss1 * (1.f / 128.f) - mu1 * mu1;
        float inv0 = 1.f / sqrtf(var0 + EPS_LN);
        float inv1 = 1.f / sqrtf(var1 + EPS_LN);
        float d0 = 0.f, d1 = 0.f;
        #pragma unroll
        for (int j = 0; j < 16; j++) {
            int col = tcol * 4 + (j >> 2) * 32 + (j & 3);
            float g = ln_g[col], bb = ln_b[col], w2 = Ws2[col];
            float y0 = (acc0[j] - mu0) * inv0 * g + bb;
            float y1 = (acc1[j] - mu1) * inv1 * g + bb;
            y0 = (y0 >= 0.f) ? y0 : NEG_SLOPE * y0;
            y1 = (y1 >= 0.f) ? y1 : NEG_SLOPE * y1;
            d0 += y0 * w2; d1 += y1 * w2;
        }
        #pragma unroll
        for (int m = 1; m < 8; m <<= 1) {
            d0 += __shfl_xor(d0, m); d1 += __shfl_xor(d1, m);
        }
        if (tcol == 0) {
            rawS[2 * trow]     = d0 + bs2[0];
            rawS[2 * trow + 1] = d1 + bs2[0];
        }
    }

    // ================= GEMM 2: eh = relu(EI @ Wp + bp) =================
    #pragma unroll
    for (int j = 0; j < 16; j++) { acc0[j] = 0.f; acc1[j] = 0.f; }
    for (int k = 0; k < 131; k++) {
        float a0 = EIr0[k];
        float a1 = EIr1[k];
        const float* wrow = &Wp[k * 128 + tcol * 4];
        #pragma unroll
        for (int j = 0; j < 4; j++) {
            float4 w = ld4(wrow + j * 32);
            acc0[j*4+0] += a0 * w.x; acc0[j*4+1] += a0 * w.y;
            acc0[j*4+2] += a0 * w.z; acc0[j*4+3] += a0 * w.w;
            acc1[j*4+0] += a1 * w.x; acc1[j*4+1] += a1 * w.y;
            acc1[j*4+2] += a1 * w.z; acc1[j*4+3] += a1 * w.w;
        }
    }
    __syncthreads();                       // all EI reads done; ehT may now alias EI
    #pragma unroll
    for (int j = 0; j < 16; j++) {
        int col = tcol * 4 + (j >> 2) * 32 + (j & 3);
        float b = bp[col];
        ehT[col * EHT_STRIDE + 2 * trow]     = fmaxf(acc0[j] + b, 0.f);
        ehT[col * EHT_STRIDE + 2 * trow + 1] = fmaxf(acc1[j] + b, 0.f);
    }
    __syncthreads();

    // ================= Gating: identical per-(e,m) FMA chains, new schedule =================
    {
        int gtr = t >> 4, gtc = t & 15;    // acc tile: edges 4*gtr+i, m 4*gtc+j
        int grow = t >> 2, gq = t & 3;     // p-phase: round-1 mapping
        float rp0 = hdr[1], rp1 = hdr[2], rp2 = hdr[3];
        float regp[3] = { rp0, rp1, rp2 };
        float gc = 0.f;
        for (int rr = 0; rr < 3; rr++) {
            float acc[16];
            #pragma unroll
            for (int j = 0; j < 16; j++) acc[j] = 0.f;
            const float* wg = Wg1 + rr * (128 * 64) + 4 * gtc;
            const float* ep = ehT + 4 * gtr;
            for (int kk = 0; kk < 128; kk++) {
                float4 av = ld4(ep + kk * EHT_STRIDE);
                float4 bv = ld4(wg + kk * 64);
                acc[0]  += av.x * bv.x; acc[1]  += av.x * bv.y; acc[2]  += av.x * bv.z; acc[3]  += av.x * bv.w;
                acc[4]  += av.y * bv.x; acc[5]  += av.y * bv.y; acc[6]  += av.y * bv.z; acc[7]  += av.y * bv.w;
                acc[8]  += av.z * bv.x; acc[9]  += av.z * bv.y; acc[10] += av.z * bv.z; acc[11] += av.z * bv.w;
                acc[12] += av.w * bv.x; acc[13] += av.w * bv.y; acc[14] += av.w * bv.z; acc[15] += av.w * bv.w;
            }
            __syncthreads();               // prior regime's p-phase reads done
            #pragma unroll
            for (int j = 0; j < 4; j++) {
                float b = bg1[rr * 64 + 4 * gtc + j];
                Gbuf[(4 * gtr + 0) * 65 + 4 * gtc + j] = fmaxf(acc[0  + j] + b, 0.f);
                Gbuf[(4 * gtr + 1) * 65 + 4 * gtc + j] = fmaxf(acc[4  + j] + b, 0.f);
                Gbuf[(4 * gtr + 2) * 65 + 4 * gtc + j] = fmaxf(acc[8  + j] + b, 0.f);
                Gbuf[(4 * gtr + 3) * 65 + 4 * gtc + j] = fmaxf(acc[12 + j] + b, 0.f);
            }
            __syncthreads();
            // p-phase: round-1 lane mapping and add order
            float p = 0.f;
            #pragma unroll
            for (int j = 0; j < 16; j++) {
                int m = gq * 4 + (j >> 2) * 16 + (j & 3);
                float g1 = Gbuf[grow * 65 + m];
                p += g1 * Wg2[rr * 64 + m];
            }
            p += __shfl_xor(p, 1);
            p += __shfl_xor(p, 2);
            float gate = 1.f / (1.f + expf(-(p + bg2[rr])));
            gc += gate * regp[rr];
        }
        if (gq == 0) gateC[grow] = gc;
    }
    __syncthreads();

    if (t < 64) {
        float amp = hdr[4];
        scores[e0 + t] = rawS[t] * gateC[t] * amp;
    }
}

// ---------------- Kernel D: per-row dedup + softmax + stable top-k ----------------
__global__ __launch_bounds__(64) void finalize_kernel(
    const int* __restrict__ tgt_idx, const float* __restrict__ scores,
    float* __restrict__ out_w, float* __restrict__ out_i)
{
    __shared__ int   tl[32];
    __shared__ float pl[32];
    int j = threadIdx.x;
    int row = blockIdx.x;
    bool lane_active = (j < 32);
    int   tg = 0;
    float s  = -INFINITY;
    if (lane_active) {
        tg = tgt_idx[row * 32 + j];
        s  = scores[row * 32 + j];
        tl[j] = tg;
    }
    __syncthreads();

    bool alive = false;
    if (lane_active) {
        alive = true;
        for (int j2 = j + 1; j2 < 32; j2++)
            if (tl[j2] == tg) { alive = false; break; }
    }
    float z = (lane_active && alive) ? s * (1.f / TEMP) : -INFINITY;
    float m = z;
    #pragma unroll
    for (int mm = 1; mm < 64; mm <<= 1) m = fmaxf(m, __shfl_xor(m, mm));
    float p = (lane_active && alive) ? expf(z - m) : 0.f;
    float sum = p;
    #pragma unroll
    for (int mm = 1; mm < 64; mm <<= 1) sum += __shfl_xor(sum, mm);
    p = p / sum;
    if (lane_active) pl[j] = alive ? p : -1.f;
    __syncthreads();

    int rank = 0, dcount = 0;
    for (int j2 = 0; j2 < 32; j2++) {
        float pj = pl[j2];
        if (pj >= 0.f) {
            dcount++;
            if (lane_active && alive) {
                if (pj > p || (pj == p && tl[j2] < tg)) rank++;
            }
        }
    }
    if (lane_active && alive) {
        out_w[row * 32 + rank] = (p > W_THRESH) ? p : 0.f;
        out_i[row * 32 + rank] = (float)tg;
    }
    if (j == 0) {
        int c = 0;
        for (int slot = dcount; slot < 32; slot++) {
            for (;;) {
                bool found = false;
                for (int q = 0; q < 32; q++) if (tl[q] == c) { found = true; break; }
                if (!found) break;
                c++;
            }
            out_w[row * 32 + slot] = 0.f;
            out_i[row * 32 + slot] = (float)c;
            c++;
        }
    }
}

extern "C" void kernel_launch(void* const* d_in, const int* in_sizes, int n_in,
                              void* d_out, int out_size, void* d_ws, size_t ws_size,
                              hipStream_t stream)
{
    const float* x          = (const float*)d_in[0];
    const int*   edge_index = (const int*)  d_in[1];
    const float* edge_attr  = (const float*)d_in[2];
    const float* Ws1 = (const float*)d_in[3];
    const float* bs1 = (const float*)d_in[4];
    const float* ln_g = (const float*)d_in[5];
    const float* ln_b = (const float*)d_in[6];
    const float* Ws2 = (const float*)d_in[7];
    const float* bs2 = (const float*)d_in[8];
    const float* Wp  = (const float*)d_in[9];
    const float* bp  = (const float*)d_in[10];
    const float* Wr1 = (const float*)d_in[11];
    const float* br1 = (const float*)d_in[12];
    const float* Wr2 = (const float*)d_in[13];
    const float* br2 = (const float*)d_in[14];
    const float* Wg1 = (const float*)d_in[15];
    const float* bg1 = (const float*)d_in[16];
    const float* Wg2 = (const float*)d_in[17];
    const float* bg2 = (const float*)d_in[18];
    const float* Wc1 = (const float*)d_in[19];
    const float* bc1 = (const float*)d_in[20];
    const float* Wc2 = (const float*)d_in[21];
    const float* bc2 = (const float*)d_in[22];

    float* hdr    = (float*)d_ws;
    float* scores = hdr + 128;
    const int* tgt = edge_index + EE;   // row 1 of edge_index

    hipMemsetAsync(d_ws, 0, 512, stream);
    stats_kernel<<<128, 256, 0, stream>>>(x, Wc1, bc1, Wc2, bc2, hdr);
    regime_kernel<<<1, 128, 0, stream>>>(Wr1, br1, Wr2, br2, hdr);
    edge_score_kernel<<<EE / 64, 256, 0, stream>>>(
        x, tgt, edge_attr, Ws1, bs1, ln_g, ln_b, Ws2, bs2, Wp, bp,
        Wg1, bg1, Wg2, bg2, hdr, scores);
    finalize_kernel<<<NN, 64, 0, stream>>>(
        tgt, scores, (float*)d_out, (float*)d_out + NN * KK);
}

// Round 4
// 517.770 us; speedup vs baseline: 1.6052x; 1.6052x over previous
//
#include <hip/hip_runtime.h>
#include <hip/hip_bf16.h>
#include <math.h>

#define NN 8192
#define FF 64
#define HH 128
#define RR 3
#define DEG 32
#define KK 32
#define EE (NN*DEG)
#define DD 131            // 2F+3
#define TEMP 0.3f
#define NEG_SLOPE 0.2f
#define EPS_LN 1e-5f
#define W_THRESH 1e-6f

__device__ __forceinline__ float4 ld4(const float* p) { return *(const float4*)p; }

// ws layout (floats): [0]=contagion_sum [1..3]=regime_probs [4]=amp [8..71]=colsum
// [128 .. 128+E) = edge scores
// [128+E ..) = PA1[N][128], PA2[N][128]  (prefix-sum tables, raw, no bias)

// ---------------- Kernel A: column sums of x + contagion level ----------------
__global__ __launch_bounds__(256) void stats_kernel(
    const float* __restrict__ x, const float* __restrict__ Wc1,
    const float* __restrict__ bc1, const float* __restrict__ Wc2,
    const float* __restrict__ bc2, float* __restrict__ hdr)
{
    __shared__ float xs[64 * 65];
    __shared__ float wl[64 * 128];
    __shared__ float cs[4][64];
    int t = threadIdx.x;
    int n0 = blockIdx.x * 64;

    for (int i = 0; i < 16; i++) {
        int flat = t + i * 256;
        int r = flat >> 6, c = flat & 63;
        xs[r * 65 + c] = x[(n0 + r) * 64 + c];
    }
    for (int i = 0; i < 32; i++) {
        int flat = t + i * 256;
        wl[flat] = Wc1[flat];
    }
    __syncthreads();

    {
        int col = t & 63, g = t >> 6;
        float ps = 0.f;
        for (int r = g * 16; r < g * 16 + 16; r++) ps += xs[r * 65 + col];
        cs[g][col] = ps;
    }
    __syncthreads();
    if (t < 64) {
        float v = cs[0][t] + cs[1][t] + cs[2][t] + cs[3][t];
        atomicAdd(&hdr[8 + t], v);
    }

    int r = t >> 2, q = t & 3;
    float accl = 0.f;
    for (int hh = 0; hh < 32; hh++) {
        int h = hh * 4 + q;
        float s = bc1[h];
        for (int i = 0; i < 64; i++) s += xs[r * 65 + i] * wl[i * 128 + h];
        accl += fmaxf(s, 0.f) * Wc2[h];
    }
    accl += __shfl_xor(accl, 1);
    accl += __shfl_xor(accl, 2);
    if (q == 0) {
        float lvl = 1.f / (1.f + expf(-(accl + bc2[0])));
        atomicAdd(&hdr[0], lvl);
    }
}

// ---------------- Kernel B: regime probs + amp ----------------
__global__ __launch_bounds__(128) void regime_kernel(
    const float* __restrict__ Wr1, const float* __restrict__ br1,
    const float* __restrict__ Wr2, const float* __restrict__ br2,
    float* __restrict__ hdr)
{
    __shared__ float gsl[64];
    __shared__ float t1[128];
    int t = threadIdx.x;
    if (t < 64) gsl[t] = hdr[8 + t] * (1.f / (float)NN);
    __syncthreads();
    float a = br1[t];
    for (int i = 0; i < 64; i++) a += gsl[i] * Wr1[i * 128 + t];
    t1[t] = fmaxf(a, 0.f);
    __syncthreads();
    if (t < 3) {
        float v = br2[t];
        for (int h = 0; h < 128; h++) v += t1[h] * Wr2[h * 3 + t];
        gsl[32 + t] = v;
    }
    __syncthreads();
    if (t == 0) {
        float v0 = gsl[32], v1 = gsl[33], v2 = gsl[34];
        float m = fmaxf(v0, fmaxf(v1, v2));
        float e0 = expf(v0 - m), e1 = expf(v1 - m), e2 = expf(v2 - m);
        float inv = 1.f / (e0 + e1 + e2);
        hdr[1] = e0 * inv; hdr[2] = e1 * inv; hdr[3] = e2 * inv;
        hdr[4] = 1.f + 0.5f * (hdr[0] * (1.f / (float)NN));
    }
}

// ---------------- Prefix tables: PA[n][c] = sum_{k<64} x[n][k] * W[k][c] ----------------
// Exact same fmac chain as the edge kernel's k=0..63 portion in round 1.
// grid = (N/32)*2; blockIdx&1: 0 -> Ws1 (PA1), 1 -> Wp (PA2). No bias (added later).
__global__ __launch_bounds__(256) void partial_kernel(
    const float* __restrict__ x, const float* __restrict__ Ws1,
    const float* __restrict__ Wp, float* __restrict__ PA)
{
    __shared__ float xs[32 * 65];
    __shared__ float wl[64 * 128];
    int t = threadIdx.x;
    int which = blockIdx.x & 1;
    int n0 = (blockIdx.x >> 1) * 32;
    const float* base = which ? Wp : Ws1;

    for (int i = t; i < 2048; i += 256)
        xs[(i >> 6) * 65 + (i & 63)] = x[n0 * 64 + i];
    for (int it = 0; it < 8; it++) {
        int flat = (t + it * 256) * 4;
        *(float4*)&wl[flat] = ld4(&base[flat]);
    }
    __syncthreads();

    int row = t >> 3, colg = t & 7;
    float acc[16];
    #pragma unroll
    for (int j = 0; j < 16; j++) acc[j] = 0.f;
    const float* xr = &xs[row * 65];
    for (int k = 0; k < 64; k++) {
        float a = xr[k];
        const float* wr = &wl[k * 128 + colg * 16];
        #pragma unroll
        for (int jj = 0; jj < 4; jj++) {
            float4 w = ld4(wr + 4 * jj);
            acc[4*jj+0] += a * w.x; acc[4*jj+1] += a * w.y;
            acc[4*jj+2] += a * w.z; acc[4*jj+3] += a * w.w;
        }
    }
    float* outp = PA + (size_t)which * (NN * 128) + (size_t)(n0 + row) * 128 + colg * 16;
    #pragma unroll
    for (int j = 0; j < 16; j++) outp[j] = acc[j];
}

// ---------------- Edge-score kernel: prefix-init fused GEMMs + tiled gating ----------------
// block = 256 threads, 64 edges (2 srcs), grid = E/64.
// LDS pool (floats), phase A: EIB[64][76] @0 (4864), WPan[2][24][128] @4864 (6144)
//                  phase B: ehT[128][68] @0 (8704), WgG union @8704 (4352)
//                  persistent: rawS @13056, gateC @13120;  pool = 13184 fl = 52736 B
#define EIB_STRIDE 76
#define EHT_STRIDE 68
__global__ __launch_bounds__(256) void edge_score_kernel(
    const int* __restrict__ tgt_idx, const float* __restrict__ edge_attr,
    const float* __restrict__ x,
    const float* __restrict__ Ws1, const float* __restrict__ bs1,
    const float* __restrict__ ln_g, const float* __restrict__ ln_b,
    const float* __restrict__ Ws2, const float* __restrict__ bs2,
    const float* __restrict__ Wp, const float* __restrict__ bp,
    const float* __restrict__ Wg1, const float* __restrict__ bg1,
    const float* __restrict__ Wg2, const float* __restrict__ bg2,
    const float* __restrict__ PA1, const float* __restrict__ PA2,
    const float* __restrict__ hdr, float* __restrict__ scores)
{
    __shared__ float pool[13184];
    float* EIB   = pool;            // [64][EIB_STRIDE]
    float* WPan  = pool + 4864;     // [2][24][128]
    float* ehT   = pool;            // [128][EHT_STRIDE] (phase B)
    float* WgG   = pool + 8704;     // union: WgPan[64][64] (4096) / Gbuf[64][EHT_STRIDE]
    float* rawS  = pool + 13056;    // [64]
    float* gateC = pool + 13120;    // [64]

    int t = threadIdx.x;
    int e0 = blockIdx.x * 64;

    // ---- stage shifted edge input: col k <-> original k+64 ----
    // cols 0..63 = x[tgt], 64..66 = edge_attr, 67..75 = 0
    {
        int r = t >> 2, q = t & 3;
        int ge = e0 + r;
        int tg = tgt_idx[ge];
        for (int ii = q; ii < EIB_STRIDE; ii += 4) {
            float v;
            if (ii < 64) v = x[tg * 64 + ii];
            else if (ii < 67) v = edge_attr[ge * 3 + (ii - 64)];
            else v = 0.f;
            EIB[r * EIB_STRIDE + ii] = v;
        }
    }

    int tcol = t & 7, trow = t >> 3;   // cols: tcol*4 + jj*32 + c ; rows: 2*trow, 2*trow+1
    const float* EIr0 = &EIB[(2 * trow) * EIB_STRIDE];
    const float* EIr1 = EIr0 + EIB_STRIDE;
    int src0 = (e0 + 2 * trow) >> 5;
    int src1 = (e0 + 2 * trow + 1) >> 5;

    float accs0[16], accs1[16], accp0[16], accp1[16];

    // ---- init accumulators from prefix tables (exact chain state after k=63) ----
    {
        const float* p1a = &PA1[(size_t)src0 * 128 + tcol * 4];
        const float* p1b = &PA1[(size_t)src1 * 128 + tcol * 4];
        const float* p2a = &PA2[(size_t)src0 * 128 + tcol * 4];
        const float* p2b = &PA2[(size_t)src1 * 128 + tcol * 4];
        #pragma unroll
        for (int jj = 0; jj < 4; jj++) {
            float4 v;
            v = ld4(p1a + jj * 32);
            accs0[4*jj+0]=v.x; accs0[4*jj+1]=v.y; accs0[4*jj+2]=v.z; accs0[4*jj+3]=v.w;
            v = ld4(p1b + jj * 32);
            accs1[4*jj+0]=v.x; accs1[4*jj+1]=v.y; accs1[4*jj+2]=v.z; accs1[4*jj+3]=v.w;
            v = ld4(p2a + jj * 32);
            accp0[4*jj+0]=v.x; accp0[4*jj+1]=v.y; accp0[4*jj+2]=v.z; accp0[4*jj+3]=v.w;
            v = ld4(p2b + jj * 32);
            accp1[4*jj+0]=v.x; accp1[4*jj+1]=v.y; accp1[4*jj+2]=v.z; accp1[4*jj+3]=v.w;
        }
    }

    // ---- fused k-loop: k' = 0..71 (original k = 64..135; rows >= 131 are zero) ----
    for (int p = 0; p < 3; p++) {
        __syncthreads();
        #pragma unroll
        for (int i = 0; i < 6; i++) {
            int fid = i * 256 + t;             // float4 id, 0..1535
            int mat = (fid >= 768) ? 1 : 0;
            int loc = fid - mat * 768;
            int pr = loc >> 5;                 // 0..23
            int pc = (loc & 31) * 4;
            int wrow = 64 + p * 24 + pr;
            const float* Wsrc = mat ? Wp : Ws1;
            float4 w = (wrow < 131) ? ld4(&Wsrc[wrow * 128 + pc])
                                    : make_float4(0.f, 0.f, 0.f, 0.f);
            *(float4*)&WPan[mat * 3072 + pr * 128 + pc] = w;
        }
        __syncthreads();
        for (int kk = 0; kk < 24; kk++) {
            int k = p * 24 + kk;
            float a0 = EIr0[k];
            float a1 = EIr1[k];
            const float* ws = &WPan[kk * 128 + tcol * 4];
            const float* wq = &WPan[3072 + kk * 128 + tcol * 4];
            #pragma unroll
            for (int jj = 0; jj < 4; jj++) {
                float4 w1 = ld4(ws + jj * 32);
                accs0[jj*4+0] += a0 * w1.x; accs0[jj*4+1] += a0 * w1.y;
                accs0[jj*4+2] += a0 * w1.z; accs0[jj*4+3] += a0 * w1.w;
                accs1[jj*4+0] += a1 * w1.x; accs1[jj*4+1] += a1 * w1.y;
                accs1[jj*4+2] += a1 * w1.z; accs1[jj*4+3] += a1 * w1.w;
                float4 w2 = ld4(wq + jj * 32);
                accp0[jj*4+0] += a0 * w2.x; accp0[jj*4+1] += a0 * w2.y;
                accp0[jj*4+2] += a0 * w2.z; accp0[jj*4+3] += a0 * w2.w;
                accp1[jj*4+0] += a1 * w2.x; accp1[jj*4+1] += a1 * w2.y;
                accp1[jj*4+2] += a1 * w2.z; accp1[jj*4+3] += a1 * w2.w;
            }
        }
    }

    // ---- +bias, LayerNorm, LeakyReLU, dot Ws2 (verbatim round-1) ----
    {
        float s0 = 0.f, ss0 = 0.f, s1 = 0.f, ss1 = 0.f;
        #pragma unroll
        for (int j = 0; j < 16; j++) {
            int col = tcol * 4 + (j >> 2) * 32 + (j & 3);
            float b = bs1[col];
            accs0[j] += b; accs1[j] += b;
            s0 += accs0[j]; ss0 += accs0[j] * accs0[j];
            s1 += accs1[j]; ss1 += accs1[j] * accs1[j];
        }
        #pragma unroll
        for (int m = 1; m < 8; m <<= 1) {
            s0 += __shfl_xor(s0, m);  ss0 += __shfl_xor(ss0, m);
            s1 += __shfl_xor(s1, m);  ss1 += __shfl_xor(ss1, m);
        }
        float mu0 = s0 * (1.f / 128.f), mu1 = s1 * (1.f / 128.f);
        float var0 = ss0 * (1.f / 128.f) - mu0 * mu0;
        float var1 = ss1 * (1.f / 128.f) - mu1 * mu1;
        float inv0 = 1.f / sqrtf(var0 + EPS_LN);
        float inv1 = 1.f / sqrtf(var1 + EPS_LN);
        float d0 = 0.f, d1 = 0.f;
        #pragma unroll
        for (int j = 0; j < 16; j++) {
            int col = tcol * 4 + (j >> 2) * 32 + (j & 3);
            float g = ln_g[col], bb = ln_b[col], w2 = Ws2[col];
            float y0 = (accs0[j] - mu0) * inv0 * g + bb;
            float y1 = (accs1[j] - mu1) * inv1 * g + bb;
            y0 = (y0 >= 0.f) ? y0 : NEG_SLOPE * y0;
            y1 = (y1 >= 0.f) ? y1 : NEG_SLOPE * y1;
            d0 += y0 * w2; d1 += y1 * w2;
        }
        #pragma unroll
        for (int m = 1; m < 8; m <<= 1) {
            d0 += __shfl_xor(d0, m); d1 += __shfl_xor(d1, m);
        }
        if (tcol == 0) {
            rawS[2 * trow]     = d0 + bs2[0];
            rawS[2 * trow + 1] = d1 + bs2[0];
        }
    }

    __syncthreads();                    // EIB/WPan reads complete; ehT may overwrite
    #pragma unroll
    for (int j = 0; j < 16; j++) {
        int col = tcol * 4 + (j >> 2) * 32 + (j & 3);
        float b = bp[col];
        ehT[col * EHT_STRIDE + 2 * trow]     = fmaxf(accp0[j] + b, 0.f);
        ehT[col * EHT_STRIDE + 2 * trow + 1] = fmaxf(accp1[j] + b, 0.f);
    }

    // ---- gating: 4 edges x 4 m register tile; per-(e,m) k-ascending chains ----
    {
        int gtr = t >> 4, gtc = t & 15;    // edges 4*gtr+i ; m 4*gtc+j
        int grow = t >> 2, gq = t & 3;     // p-phase: round-1 lane mapping
        float rp0 = hdr[1], rp1 = hdr[2], rp2 = hdr[3];
        float gc = 0.f;
        for (int rr = 0; rr < 3; rr++) {
            float acc[16];
            #pragma unroll
            for (int j = 0; j < 16; j++) acc[j] = 0.f;
            for (int p = 0; p < 2; p++) {
                __syncthreads();           // also covers ehT-store on first pass
                #pragma unroll
                for (int i = 0; i < 4; i++) {
                    int fid = i * 256 + t;             // 0..1023
                    int pr = fid >> 4;                 // 0..63
                    int pc = (fid & 15) * 4;
                    *(float4*)&WgG[pr * 64 + pc] =
                        ld4(&Wg1[(size_t)(rr * 128 + p * 64 + pr) * 64 + pc]);
                }
                __syncthreads();
                for (int kk = 0; kk < 64; kk++) {
                    float4 av = ld4(&ehT[(p * 64 + kk) * EHT_STRIDE + 4 * gtr]);
                    float4 bv = ld4(&WgG[kk * 64 + 4 * gtc]);
                    acc[0]  += av.x * bv.x; acc[1]  += av.x * bv.y; acc[2]  += av.x * bv.z; acc[3]  += av.x * bv.w;
                    acc[4]  += av.y * bv.x; acc[5]  += av.y * bv.y; acc[6]  += av.y * bv.z; acc[7]  += av.y * bv.w;
                    acc[8]  += av.z * bv.x; acc[9]  += av.z * bv.y; acc[10] += av.z * bv.z; acc[11] += av.z * bv.w;
                    acc[12] += av.w * bv.x; acc[13] += av.w * bv.y; acc[14] += av.w * bv.z; acc[15] += av.w * bv.w;
                }
            }
            __syncthreads();               // WgPan reads done; Gbuf overwrites region
            #pragma unroll
            for (int j = 0; j < 4; j++) {
                float b = bg1[rr * 64 + 4 * gtc + j];
                float4 g;
                g.x = fmaxf(acc[0  + j] + b, 0.f);
                g.y = fmaxf(acc[4  + j] + b, 0.f);
                g.z = fmaxf(acc[8  + j] + b, 0.f);
                g.w = fmaxf(acc[12 + j] + b, 0.f);
                *(float4*)&WgG[(4 * gtc + j) * EHT_STRIDE + 4 * gtr] = g;
            }
            __syncthreads();
            // p-phase: round-1 lane mapping and add order
            float pacc = 0.f;
            #pragma unroll
            for (int j = 0; j < 16; j++) {
                int m = gq * 4 + (j >> 2) * 16 + (j & 3);
                pacc += WgG[m * EHT_STRIDE + grow] * Wg2[rr * 64 + m];
            }
            pacc += __shfl_xor(pacc, 1);
            pacc += __shfl_xor(pacc, 2);
            float gate = 1.f / (1.f + expf(-(pacc + bg2[rr])));
            float rpr = (rr == 0) ? rp0 : ((rr == 1) ? rp1 : rp2);
            gc += gate * rpr;
        }
        if (gq == 0) gateC[grow] = gc;
    }
    __syncthreads();

    if (t < 64) scores[e0 + t] = rawS[t] * gateC[t] * hdr[4];
}

// ---------------- Kernel D: per-row dedup + softmax + stable top-k ----------------
__global__ __launch_bounds__(64) void finalize_kernel(
    const int* __restrict__ tgt_idx, const float* __restrict__ scores,
    float* __restrict__ out_w, float* __restrict__ out_i)
{
    __shared__ int   tl[32];
    __shared__ float pl[32];
    int j = threadIdx.x;
    int row = blockIdx.x;
    bool lane_active = (j < 32);
    int   tg = 0;
    float s  = -INFINITY;
    if (lane_active) {
        tg = tgt_idx[row * 32 + j];
        s  = scores[row * 32 + j];
        tl[j] = tg;
    }
    __syncthreads();

    bool alive = false;
    if (lane_active) {
        alive = true;
        for (int j2 = j + 1; j2 < 32; j2++)
            if (tl[j2] == tg) { alive = false; break; }
    }
    float z = (lane_active && alive) ? s * (1.f / TEMP) : -INFINITY;
    float m = z;
    #pragma unroll
    for (int mm = 1; mm < 64; mm <<= 1) m = fmaxf(m, __shfl_xor(m, mm));
    float p = (lane_active && alive) ? expf(z - m) : 0.f;
    float sum = p;
    #pragma unroll
    for (int mm = 1; mm < 64; mm <<= 1) sum += __shfl_xor(sum, mm);
    p = p / sum;
    if (lane_active) pl[j] = alive ? p : -1.f;
    __syncthreads();

    int rank = 0, dcount = 0;
    for (int j2 = 0; j2 < 32; j2++) {
        float pj = pl[j2];
        if (pj >= 0.f) {
            dcount++;
            if (lane_active && alive) {
                if (pj > p || (pj == p && tl[j2] < tg)) rank++;
            }
        }
    }
    if (lane_active && alive) {
        out_w[row * 32 + rank] = (p > W_THRESH) ? p : 0.f;
        out_i[row * 32 + rank] = (float)tg;
    }
    if (j == 0) {
        int c = 0;
        for (int slot = dcount; slot < 32; slot++) {
            for (;;) {
                bool found = false;
                for (int q = 0; q < 32; q++) if (tl[q] == c) { found = true; break; }
                if (!found) break;
                c++;
            }
            out_w[row * 32 + slot] = 0.f;
            out_i[row * 32 + slot] = (float)c;
            c++;
        }
    }
}

extern "C" void kernel_launch(void* const* d_in, const int* in_sizes, int n_in,
                              void* d_out, int out_size, void* d_ws, size_t ws_size,
                              hipStream_t stream)
{
    const float* x          = (const float*)d_in[0];
    const int*   edge_index = (const int*)  d_in[1];
    const float* edge_attr  = (const float*)d_in[2];
    const float* Ws1 = (const float*)d_in[3];
    const float* bs1 = (const float*)d_in[4];
    const float* ln_g = (const float*)d_in[5];
    const float* ln_b = (const float*)d_in[6];
    const float* Ws2 = (const float*)d_in[7];
    const float* bs2 = (const float*)d_in[8];
    const float* Wp  = (const float*)d_in[9];
    const float* bp  = (const float*)d_in[10];
    const float* Wr1 = (const float*)d_in[11];
    const float* br1 = (const float*)d_in[12];
    const float* Wr2 = (const float*)d_in[13];
    const float* br2 = (const float*)d_in[14];
    const float* Wg1 = (const float*)d_in[15];
    const float* bg1 = (const float*)d_in[16];
    const float* Wg2 = (const float*)d_in[17];
    const float* bg2 = (const float*)d_in[18];
    const float* Wc1 = (const float*)d_in[19];
    const float* bc1 = (const float*)d_in[20];
    const float* Wc2 = (const float*)d_in[21];
    const float* bc2 = (const float*)d_in[22];

    float* hdr    = (float*)d_ws;
    float* scores = hdr + 128;
    float* tabs   = scores + EE;            // PA1, then PA2
    const int* tgt = edge_index + EE;       // row 1 of edge_index

    hipMemsetAsync(d_ws, 0, 512, stream);
    stats_kernel<<<128, 256, 0, stream>>>(x, Wc1, bc1, Wc2, bc2, hdr);
    regime_kernel<<<1, 128, 0, stream>>>(Wr1, br1, Wr2, br2, hdr);
    partial_kernel<<<(NN / 32) * 2, 256, 0, stream>>>(x, Ws1, Wp, tabs);
    edge_score_kernel<<<EE / 64, 256, 0, stream>>>(
        tgt, edge_attr, x, Ws1, bs1, ln_g, ln_b, Ws2, bs2, Wp, bp,
        Wg1, bg1, Wg2, bg2, tabs, tabs + (size_t)NN * 128, hdr, scores);
    finalize_kernel<<<NN, 64, 0, stream>>>(
        tgt, scores, (float*)d_out, (float*)d_out + NN * KK);
}